// Round 1
// baseline (170.399 us; speedup 1.0000x reference)
//
#include <hip/hip_runtime.h>
#include <math.h>

#define IMG  128
#define NCH  64
#define PADC 4
#define PADW 136               // 128 + 2*4
#define PLANE (PADW * PADW)    // 18496
#define NPIX (IMG * IMG)       // 16384

// ---------------------------------------------------------------------------
// K1: phi[b][c][y][x] = sum_i w[c][i] * u[b][i][y][x], stored into padded
// planes phi_pad[2][64][136][136] (border pre-zeroed by memset).
// Thread = (b, oc=8-channel chunk, y, x). u loads coalesced over x; w reads
// are wave-uniform -> scalar loads.
// ---------------------------------------------------------------------------
__global__ __launch_bounds__(256) void k_phi(const float* __restrict__ u,
                                             const float* __restrict__ w,
                                             float* __restrict__ phi) {
  int t  = blockIdx.x * 256 + threadIdx.x;   // 2*8*128*128 = 262144 threads
  int x  = t & 127;
  int y  = (t >> 7) & 127;
  int oc = (t >> 14) & 7;
  int b  = t >> 17;

  const float* up = u + (size_t)(b * NCH) * NPIX + y * IMG + x;
  const float* wr = w + oc * 8 * NCH;

  float acc[8];
#pragma unroll
  for (int k = 0; k < 8; ++k) acc[k] = 0.f;

#pragma unroll 16
  for (int i = 0; i < NCH; ++i) {
    float uv = up[(size_t)i * NPIX];
#pragma unroll
    for (int k = 0; k < 8; ++k) acc[k] += wr[k * NCH + i] * uv;
  }

  float* pp = phi + (size_t)(b * NCH + oc * 8) * PLANE + (y + PADC) * PADW + (x + PADC);
#pragma unroll
  for (int k = 0; k < 8; ++k) pp[(size_t)k * PLANE] = acc[k];
}

// ---------------------------------------------------------------------------
// K2: C_d(x) = sum_c phi[c,x] * phi[c,x+d] for all 49 offsets d=(dy,dx),
// dy,dx in [-3,3]. Thread = (b, dy, y, 4-consecutive-x quad). Per channel:
// 1 float4 own-load + 3 float4 neighbor-loads (span x0-4..x0+7), 28 FMAs.
// Padded phi -> no bounds checks, all loads 16B-aligned.
// Output planes Cb[b][d][y][x] (d = (dy+3)*7 + (dx+3)).
// ---------------------------------------------------------------------------
__global__ __launch_bounds__(256) void k_corr(const float* __restrict__ phi,
                                              float* __restrict__ Cb) {
  int t   = blockIdx.x * 256 + threadIdx.x;  // 2*7*128*32 = 57344 threads
  int xq  = t & 31;
  int y   = (t >> 5) & 127;
  int r   = t >> 12;            // 0..13
  int dyI = r % 7;
  int b   = r / 7;
  int x0  = xq * 4;
  int dy  = dyI - 3;

  const float* own = phi + (size_t)(b * NCH) * PLANE + (y + PADC) * PADW + (x0 + PADC);
  const float* nb  = phi + (size_t)(b * NCH) * PLANE + (y + dy + PADC) * PADW + x0; // x = x0-4 .. x0+7

  float acc[4][7];
#pragma unroll
  for (int px = 0; px < 4; ++px)
#pragma unroll
    for (int dxi = 0; dxi < 7; ++dxi) acc[px][dxi] = 0.f;

#pragma unroll 2
  for (int c = 0; c < NCH; ++c) {
    float4 o4 = *(const float4*)(own + (size_t)c * PLANE);
    float4 n0 = *(const float4*)(nb + (size_t)c * PLANE);
    float4 n1 = *(const float4*)(nb + (size_t)c * PLANE + 4);
    float4 n2 = *(const float4*)(nb + (size_t)c * PLANE + 8);
    float ov[4]  = {o4.x, o4.y, o4.z, o4.w};
    float nv[12] = {n0.x, n0.y, n0.z, n0.w, n1.x, n1.y, n1.z, n1.w,
                    n2.x, n2.y, n2.z, n2.w};
#pragma unroll
    for (int px = 0; px < 4; ++px)
#pragma unroll
      for (int dxi = 0; dxi < 7; ++dxi)
        acc[px][dxi] += ov[px] * nv[px + dxi + 1];   // nv idx = (px+dx) - (-4) = px+dxi+1
  }

#pragma unroll
  for (int dxi = 0; dxi < 7; ++dxi) {
    int d = dyI * 7 + dxi;
    float4 v = make_float4(acc[0][dxi], acc[1][dxi], acc[2][dxi], acc[3][dxi]);
    *(float4*)(Cb + ((size_t)(b * 49 + d) * IMG + y) * IMG + x0) = v;
  }
}

// ---------------------------------------------------------------------------
// K3: score_d(p) = (p+d in-image) ? sum_{o in 3x3} C_d(p+o) : 0
// then softmax over the 49 scores (zeros included, matching reference), and
// store out[b][y][x][49].
// ---------------------------------------------------------------------------
__global__ __launch_bounds__(256) void k_score(const float* __restrict__ Cb,
                                               float* __restrict__ out) {
  int t = blockIdx.x * 256 + threadIdx.x;    // 2*128*128 = 32768 threads
  int x = t & 127;
  int y = (t >> 7) & 127;
  int b = t >> 14;

  float s[49];
#pragma unroll
  for (int dyI = 0; dyI < 7; ++dyI) {
    int qy = y + dyI - 3;
    bool qyv = ((unsigned)qy < (unsigned)IMG);
#pragma unroll
    for (int dxi = 0; dxi < 7; ++dxi) {
      int d  = dyI * 7 + dxi;
      int qx = x + dxi - 3;
      float sum = 0.f;
      if (qyv && ((unsigned)qx < (unsigned)IMG)) {
        const float* base = Cb + (size_t)(b * 49 + d) * NPIX;
#pragma unroll
        for (int oy = -1; oy <= 1; ++oy) {
          int yy = y + oy;
          if ((unsigned)yy < (unsigned)IMG) {
#pragma unroll
            for (int ox = -1; ox <= 1; ++ox) {
              int xx = x + ox;
              if ((unsigned)xx < (unsigned)IMG) sum += base[yy * IMG + xx];
            }
          }
        }
      }
      s[d] = sum;
    }
  }

  float m = s[0];
#pragma unroll
  for (int d = 1; d < 49; ++d) m = fmaxf(m, s[d]);
  float tot = 0.f;
#pragma unroll
  for (int d = 0; d < 49; ++d) {
    float e = __expf(s[d] - m);
    s[d] = e;
    tot += e;
  }
  float inv = 1.f / tot;
  float* op = out + (size_t)t * 49;
#pragma unroll
  for (int d = 0; d < 49; ++d) op[d] = s[d] * inv;
}

// ---------------------------------------------------------------------------
extern "C" void kernel_launch(void* const* d_in, const int* in_sizes, int n_in,
                              void* d_out, int out_size, void* d_ws, size_t ws_size,
                              hipStream_t stream) {
  const float* u = (const float*)d_in[0];
  const float* w = (const float*)d_in[1];
  float* out = (float*)d_out;

  float* phi = (float*)d_ws;                         // 2*64*18496 floats = 9.47 MB
  float* Cb  = phi + (size_t)2 * NCH * PLANE;        // 2*49*16384 floats = 6.42 MB

  // zero padded phi (borders must be 0; ws is re-poisoned before every call)
  hipMemsetAsync(d_ws, 0, (size_t)2 * NCH * PLANE * sizeof(float), stream);

  k_phi  <<<1024, 256, 0, stream>>>(u, w, phi);
  k_corr <<<224,  256, 0, stream>>>(phi, Cb);
  k_score<<<128,  256, 0, stream>>>(Cb, out);
}

// Round 3
// 122.228 us; speedup vs baseline: 1.3941x; 1.3941x over previous
//
#include <hip/hip_runtime.h>
#include <math.h>

#define IMG  128
#define NCH  64
#define PADC 4
#define PADW 136               // 128 + 2*4
#define PLANE (PADW * PADW)    // 18496
#define NPIX (IMG * IMG)       // 16384

// padded C planes: [2][49][130][136], row offset +1, col offset +4
#define CPH 130
#define CPW 136
#define CPLANE (CPH * CPW)     // 17680

// ---------------------------------------------------------------------------
// K1: phi[b][c][y][x] = sum_i w[c][i] * u[b][i][y][x], stored into padded
// planes phi_pad[2][64][136][136] (border pre-zeroed by memset).
// ---------------------------------------------------------------------------
__global__ __launch_bounds__(256) void k_phi(const float* __restrict__ u,
                                             const float* __restrict__ w,
                                             float* __restrict__ phi) {
  int t  = blockIdx.x * 256 + threadIdx.x;   // 2*8*128*128 = 262144 threads
  int x  = t & 127;
  int y  = (t >> 7) & 127;
  int oc = (t >> 14) & 7;
  int b  = t >> 17;

  const float* up = u + (size_t)(b * NCH) * NPIX + y * IMG + x;
  const float* wr = w + oc * 8 * NCH;

  float acc[8];
#pragma unroll
  for (int k = 0; k < 8; ++k) acc[k] = 0.f;

#pragma unroll 16
  for (int i = 0; i < NCH; ++i) {
    float uv = up[(size_t)i * NPIX];
#pragma unroll
    for (int k = 0; k < 8; ++k) acc[k] += wr[k * NCH + i] * uv;
  }

  float* pp = phi + (size_t)(b * NCH + oc * 8) * PLANE + (y + PADC) * PADW + (x + PADC);
#pragma unroll
  for (int k = 0; k < 8; ++k) pp[(size_t)k * PLANE] = acc[k];
}

// ---------------------------------------------------------------------------
// K2: C_d(x) = sum_c phi[c,x] * phi[c,x+d], written to padded Cpad planes.
// Thread = (b, dy, y, 4-x quad); 4 float4 loads + 28 FMAs per channel.
// ---------------------------------------------------------------------------
__global__ __launch_bounds__(256) void k_corr(const float* __restrict__ phi,
                                              float* __restrict__ Cpad) {
  int t   = blockIdx.x * 256 + threadIdx.x;  // 2*7*128*32 = 57344 threads
  int xq  = t & 31;
  int y   = (t >> 5) & 127;
  int r   = t >> 12;            // 0..13
  int dyI = r % 7;
  int b   = r / 7;
  int x0  = xq * 4;
  int dy  = dyI - 3;

  const float* own = phi + (size_t)(b * NCH) * PLANE + (y + PADC) * PADW + (x0 + PADC);
  const float* nb  = phi + (size_t)(b * NCH) * PLANE + (y + dy + PADC) * PADW + x0; // x0-4..x0+7

  float acc[4][7];
#pragma unroll
  for (int px = 0; px < 4; ++px)
#pragma unroll
    for (int dxi = 0; dxi < 7; ++dxi) acc[px][dxi] = 0.f;

#pragma unroll 2
  for (int c = 0; c < NCH; ++c) {
    float4 o4 = *(const float4*)(own + (size_t)c * PLANE);
    float4 n0 = *(const float4*)(nb + (size_t)c * PLANE);
    float4 n1 = *(const float4*)(nb + (size_t)c * PLANE + 4);
    float4 n2 = *(const float4*)(nb + (size_t)c * PLANE + 8);
    float ov[4]  = {o4.x, o4.y, o4.z, o4.w};
    float nv[12] = {n0.x, n0.y, n0.z, n0.w, n1.x, n1.y, n1.z, n1.w,
                    n2.x, n2.y, n2.z, n2.w};
#pragma unroll
    for (int px = 0; px < 4; ++px)
#pragma unroll
      for (int dxi = 0; dxi < 7; ++dxi)
        acc[px][dxi] += ov[px] * nv[px + dxi + 1];
  }

#pragma unroll
  for (int dxi = 0; dxi < 7; ++dxi) {
    int d = dyI * 7 + dxi;
    float4 v = make_float4(acc[0][dxi], acc[1][dxi], acc[2][dxi], acc[3][dxi]);
    // padded store: row y+1, col x0+4  (16B aligned: row pitch 544B, +16B)
    *(float4*)(Cpad + ((size_t)(b * 49 + d) * CPH + (y + 1)) * CPW + (x0 + 4)) = v;
  }
}

// ---------------------------------------------------------------------------
// K2.5: S_d = box3x3(C_d) via zero-padded planes; thread = 4 consecutive x.
// ---------------------------------------------------------------------------
__global__ __launch_bounds__(256) void k_box(const float* __restrict__ Cpad,
                                             float* __restrict__ S) {
  int t  = blockIdx.x * 256 + threadIdx.x;   // 2*49*128*32 = 401408 threads
  int xq = t & 31;
  int y  = (t >> 5) & 127;
  int r  = t >> 12;             // b*49+d, 0..97
  int x0 = xq * 4;

  const float* base = Cpad + ((size_t)r * CPH + y) * CPW + x0;  // rows y..y+2 (=orig y-1..y+1)

  float acc[4] = {0.f, 0.f, 0.f, 0.f};
#pragma unroll
  for (int ry = 0; ry < 3; ++ry) {
    const float* rp = base + ry * CPW;
    float4 a = *(const float4*)rp;
    float4 bq = *(const float4*)(rp + 4);
    float4 c = *(const float4*)(rp + 8);
    float v[12] = {a.x, a.y, a.z, a.w, bq.x, bq.y, bq.z, bq.w, c.x, c.y, c.z, c.w};
#pragma unroll
    for (int j = 0; j < 4; ++j)
      acc[j] += v[j + 3] + v[j + 4] + v[j + 5];   // orig cols x0+j-1..x0+j+1
  }

  *(float4*)(S + ((size_t)r * IMG + y) * IMG + x0) =
      make_float4(acc[0], acc[1], acc[2], acc[3]);
}

// ---------------------------------------------------------------------------
// K3: s[d] = (p+d in-image) ? S_d(p) : 0 ; softmax over 49; coalesced store
// via LDS staging (out layout [b,y,x,49] -> block chunk is contiguous).
// ---------------------------------------------------------------------------
__global__ __launch_bounds__(256) void k_score(const float* __restrict__ S,
                                               float* __restrict__ out) {
  __shared__ float lds[256 * 49];
  int t = blockIdx.x * 256 + threadIdx.x;    // 2*128*128 = 32768 threads
  int x = t & 127;
  int y = (t >> 7) & 127;
  int b = t >> 14;

  const float* sp = S + (size_t)b * 49 * NPIX + y * IMG + x;

  float s[49];
#pragma unroll
  for (int dyI = 0; dyI < 7; ++dyI) {
    int qy = y + dyI - 3;
    bool yv = ((unsigned)qy < (unsigned)IMG);
#pragma unroll
    for (int dxi = 0; dxi < 7; ++dxi) {
      int d  = dyI * 7 + dxi;
      int qx = x + dxi - 3;
      float v = sp[(size_t)d * NPIX];          // coalesced over x
      s[d] = (yv && ((unsigned)qx < (unsigned)IMG)) ? v : 0.f;
    }
  }

  float m = s[0];
#pragma unroll
  for (int d = 1; d < 49; ++d) m = fmaxf(m, s[d]);
  float tot = 0.f;
#pragma unroll
  for (int d = 0; d < 49; ++d) {
    float e = __expf(s[d] - m);
    s[d] = e;
    tot += e;
  }
  float inv = 1.f / tot;

  // stage to LDS pixel-major (stride 49 mod 32 = 17: conflict-free), then
  // copy the block's contiguous 12544-float chunk coalesced.
#pragma unroll
  for (int d = 0; d < 49; ++d) lds[threadIdx.x * 49 + d] = s[d] * inv;
  __syncthreads();

  float* ob = out + (size_t)blockIdx.x * (256 * 49);
  const float4* l4 = (const float4*)lds;
#pragma unroll
  for (int i = 0; i < 12; ++i) {               // 12*256 float4 = 12288 floats
    ((float4*)ob)[i * 256 + threadIdx.x] = l4[i * 256 + threadIdx.x];
  }
  ob[12288 + threadIdx.x] = lds[12288 + threadIdx.x];  // remaining 256 floats
}

// ---------------------------------------------------------------------------
extern "C" void kernel_launch(void* const* d_in, const int* in_sizes, int n_in,
                              void* d_out, int out_size, void* d_ws, size_t ws_size,
                              hipStream_t stream) {
  const float* u = (const float*)d_in[0];
  const float* w = (const float*)d_in[1];
  float* out = (float*)d_out;

  float* phi  = (float*)d_ws;                          // 2*64*18496 = 2367488 floats
  float* Cpad = phi + (size_t)2 * NCH * PLANE;         // 2*49*17680 = 1732640 floats
  float* S    = phi;                                   // alias: phi dead after k_corr
                                                       // (needs 1605632 <= 2367488)

  // zero phi + Cpad (borders must be 0; ws re-poisoned before every call)
  hipMemsetAsync(d_ws, 0,
                 ((size_t)2 * NCH * PLANE + (size_t)2 * 49 * CPLANE) * sizeof(float),
                 stream);

  k_phi  <<<1024, 256, 0, stream>>>(u, w, phi);
  k_corr <<<224,  256, 0, stream>>>(phi, Cpad);
  k_box  <<<1568, 256, 0, stream>>>(Cpad, S);
  k_score<<<128,  256, 0, stream>>>(S, out);
}

// Round 4
// 112.289 us; speedup vs baseline: 1.5175x; 1.0885x over previous
//
#include <hip/hip_runtime.h>
#include <math.h>

#define IMG  128
#define NCH  64
#define PADC 4
#define PADW 136               // 128 + 2*4
#define PLANE (PADW * PADW)    // 18496
#define NPIX (IMG * IMG)       // 16384

// padded C planes: [part][2][49][130][136], row offset +1, col offset +4
#define CPH 130
#define CPW 136
#define CPLANE (CPH * CPW)     // 17680
#define NPART 4
#define PSTRIDE ((size_t)2 * 49 * CPLANE)   // floats per part

// ---------------------------------------------------------------------------
// K1: phi[b][c][y][x] = sum_i w[c][i] * u[b][i][y][x] into padded planes
// phi_pad[2][64][136][136] (border pre-zeroed by memset).
// ---------------------------------------------------------------------------
__global__ __launch_bounds__(256) void k_phi(const float* __restrict__ u,
                                             const float* __restrict__ w,
                                             float* __restrict__ phi) {
  int t  = blockIdx.x * 256 + threadIdx.x;   // 2*8*128*128 = 262144 threads
  int x  = t & 127;
  int y  = (t >> 7) & 127;
  int oc = (t >> 14) & 7;
  int b  = t >> 17;

  const float* up = u + (size_t)(b * NCH) * NPIX + y * IMG + x;
  const float* wr = w + oc * 8 * NCH;

  float acc[8];
#pragma unroll
  for (int k = 0; k < 8; ++k) acc[k] = 0.f;

#pragma unroll 16
  for (int i = 0; i < NCH; ++i) {
    float uv = up[(size_t)i * NPIX];
#pragma unroll
    for (int k = 0; k < 8; ++k) acc[k] += wr[k * NCH + i] * uv;
  }

  float* pp = phi + (size_t)(b * NCH + oc * 8) * PLANE + (y + PADC) * PADW + (x + PADC);
#pragma unroll
  for (int k = 0; k < 8; ++k) pp[(size_t)k * PLANE] = acc[k];
}

// ---------------------------------------------------------------------------
// K2: partial C_d(x) = sum_{c in 16-chunk} phi[c,x]*phi[c,x+d], 4-way channel
// split for occupancy (229376 threads = ~14 waves/CU). Thread = (part, b, dy,
// y, 4-x quad); per channel: 4 float4 loads + 28 FMAs.
// ---------------------------------------------------------------------------
__global__ __launch_bounds__(256) void k_corr(const float* __restrict__ phi,
                                              float* __restrict__ Cpad) {
  int t   = blockIdx.x * 256 + threadIdx.x;  // 4*2*7*128*32 = 229376 threads
  int xq  = t & 31;
  int y   = (t >> 5) & 127;
  int r   = t >> 12;            // 0..55 = part*14 + b*7 + dyI
  int part = r / 14;
  int rr   = r - part * 14;
  int b    = rr / 7;
  int dyI  = rr - b * 7;
  int x0  = xq * 4;
  int dy  = dyI - 3;

  const float* pb  = phi + (size_t)(b * NCH + part * 16) * PLANE;
  const float* own = pb + (y + PADC) * PADW + (x0 + PADC);
  const float* nb  = pb + (y + dy + PADC) * PADW + x0;   // covers x0-4..x0+7

  float acc[4][7];
#pragma unroll
  for (int px = 0; px < 4; ++px)
#pragma unroll
    for (int dxi = 0; dxi < 7; ++dxi) acc[px][dxi] = 0.f;

#pragma unroll 2
  for (int c = 0; c < 16; ++c) {
    float4 o4 = *(const float4*)(own + (size_t)c * PLANE);
    float4 n0 = *(const float4*)(nb + (size_t)c * PLANE);
    float4 n1 = *(const float4*)(nb + (size_t)c * PLANE + 4);
    float4 n2 = *(const float4*)(nb + (size_t)c * PLANE + 8);
    float ov[4]  = {o4.x, o4.y, o4.z, o4.w};
    float nv[12] = {n0.x, n0.y, n0.z, n0.w, n1.x, n1.y, n1.z, n1.w,
                    n2.x, n2.y, n2.z, n2.w};
#pragma unroll
    for (int px = 0; px < 4; ++px)
#pragma unroll
      for (int dxi = 0; dxi < 7; ++dxi)
        acc[px][dxi] += ov[px] * nv[px + dxi + 1];
  }

  float* cp = Cpad + part * PSTRIDE;
#pragma unroll
  for (int dxi = 0; dxi < 7; ++dxi) {
    int d = dyI * 7 + dxi;
    float4 v = make_float4(acc[0][dxi], acc[1][dxi], acc[2][dxi], acc[3][dxi]);
    *(float4*)(cp + ((size_t)(b * 49 + d) * CPH + (y + 1)) * CPW + (x0 + 4)) = v;
  }
}

// ---------------------------------------------------------------------------
// K2.5: S_d = box3x3(sum_part Cpad_part_d); thread = 4 consecutive x.
// ---------------------------------------------------------------------------
__global__ __launch_bounds__(256) void k_box(const float* __restrict__ Cpad,
                                             float* __restrict__ S) {
  int t  = blockIdx.x * 256 + threadIdx.x;   // 2*49*128*32 = 401408 threads
  int xq = t & 31;
  int y  = (t >> 5) & 127;
  int r  = t >> 12;             // b*49+d, 0..97
  int x0 = xq * 4;

  float acc[4] = {0.f, 0.f, 0.f, 0.f};
#pragma unroll
  for (int p = 0; p < NPART; ++p) {
    const float* base = Cpad + p * PSTRIDE + ((size_t)r * CPH + y) * CPW + x0;
#pragma unroll
    for (int ry = 0; ry < 3; ++ry) {
      const float* rp = base + ry * CPW;
      float4 a = *(const float4*)rp;
      float4 bq = *(const float4*)(rp + 4);
      float4 c = *(const float4*)(rp + 8);
      float v[12] = {a.x, a.y, a.z, a.w, bq.x, bq.y, bq.z, bq.w, c.x, c.y, c.z, c.w};
#pragma unroll
      for (int j = 0; j < 4; ++j)
        acc[j] += v[j + 3] + v[j + 4] + v[j + 5];
    }
  }

  *(float4*)(S + ((size_t)r * IMG + y) * IMG + x0) =
      make_float4(acc[0], acc[1], acc[2], acc[3]);
}

// ---------------------------------------------------------------------------
// K3: s[d] = (p+d in-image) ? S_d(p) : 0 ; softmax over 49; coalesced store
// via LDS staging. 64-thread blocks so all 256 CUs get work (512 blocks).
// ---------------------------------------------------------------------------
__global__ __launch_bounds__(64) void k_score(const float* __restrict__ S,
                                              float* __restrict__ out) {
  __shared__ float lds[64 * 49];
  int t = blockIdx.x * 64 + threadIdx.x;     // 2*128*128 = 32768 threads
  int x = t & 127;
  int y = (t >> 7) & 127;
  int b = t >> 14;

  const float* sp = S + (size_t)b * 49 * NPIX + y * IMG + x;

  float s[49];
#pragma unroll
  for (int dyI = 0; dyI < 7; ++dyI) {
    int qy = y + dyI - 3;
    bool yv = ((unsigned)qy < (unsigned)IMG);
#pragma unroll
    for (int dxi = 0; dxi < 7; ++dxi) {
      int d  = dyI * 7 + dxi;
      int qx = x + dxi - 3;
      float v = sp[(size_t)d * NPIX];          // coalesced over x
      s[d] = (yv && ((unsigned)qx < (unsigned)IMG)) ? v : 0.f;
    }
  }

  float m = s[0];
#pragma unroll
  for (int d = 1; d < 49; ++d) m = fmaxf(m, s[d]);
  float tot = 0.f;
#pragma unroll
  for (int d = 0; d < 49; ++d) {
    float e = __expf(s[d] - m);
    s[d] = e;
    tot += e;
  }
  float inv = 1.f / tot;

#pragma unroll
  for (int d = 0; d < 49; ++d) lds[threadIdx.x * 49 + d] = s[d] * inv;
  __syncthreads();

  // block's out chunk = 64*49 = 3136 contiguous floats = 784 float4
  float* ob = out + (size_t)blockIdx.x * (64 * 49);
  const float4* l4 = (const float4*)lds;
#pragma unroll
  for (int i = 0; i < 12; ++i)                 // 12*64 = 768 float4
    ((float4*)ob)[i * 64 + threadIdx.x] = l4[i * 64 + threadIdx.x];
  if (threadIdx.x < 16)                        // remaining 16 float4
    ((float4*)ob)[768 + threadIdx.x] = l4[768 + threadIdx.x];
}

// ---------------------------------------------------------------------------
extern "C" void kernel_launch(void* const* d_in, const int* in_sizes, int n_in,
                              void* d_out, int out_size, void* d_ws, size_t ws_size,
                              hipStream_t stream) {
  const float* u = (const float*)d_in[0];
  const float* w = (const float*)d_in[1];
  float* out = (float*)d_out;

  float* phi  = (float*)d_ws;                          // 2*64*18496 = 2367488 floats
  float* Cpad = phi + (size_t)2 * NCH * PLANE;         // 4 parts * 1732640 floats
  float* S    = phi;                                   // alias: phi dead after k_corr
                                                       // (1605632 <= 2367488)

  // zero phi pads + all Cpad part borders (ws re-poisoned before every call)
  hipMemsetAsync(d_ws, 0,
                 ((size_t)2 * NCH * PLANE + NPART * PSTRIDE) * sizeof(float),
                 stream);

  k_phi  <<<1024, 256, 0, stream>>>(u, w, phi);
  k_corr <<<896,  256, 0, stream>>>(phi, Cpad);
  k_box  <<<1568, 256, 0, stream>>>(Cpad, S);
  k_score<<<512,  64,  0, stream>>>(S, out);
}

// Round 5
// 109.859 us; speedup vs baseline: 1.5511x; 1.0221x over previous
//
#include <hip/hip_runtime.h>
#include <math.h>

#define IMG  128
#define NCH  64
#define PADC 4
#define PADW 136               // 128 + 2*4
#define PLANE (PADW * PADW)    // 18496
#define NPIX (IMG * IMG)       // 16384

// padded C planes: [part][2][49][130][136], row offset +1, col offset +4
#define CPH 130
#define CPW 136
#define CPLANE (CPH * CPW)     // 17680
#define NPART 4
#define PSTRIDE ((size_t)2 * 49 * CPLANE)   // floats per part

// border-zero bookkeeping (pads only; interiors are fully overwritten)
#define PHI_THREADS   262144                // 2*8*128*128 compute threads
#define PHI_BPP       2112                  // phi border floats per plane
#define PHI_BTOTAL    (128 * PHI_BPP)       // 270336
#define CPAD_BPP      1296                  // Cpad border floats per plane
#define CPAD_BTOTAL   (392 * CPAD_BPP)      // 508032  (98 planes * 4 parts)
#define TOTAL_THREADS (PHI_THREADS + PHI_BTOTAL + CPAD_BTOTAL)  // 1040512

// ---------------------------------------------------------------------------
// K1: phi[b][c][y][x] = sum_i w[c][i]*u[b][i][y][x] into padded planes
// phi_pad[2][64][136][136]; extra trailing blocks zero the pad borders of
// phi and Cpad (replaces a 37 MB memset with 3.1 MB of scattered stores).
// ---------------------------------------------------------------------------
__global__ __launch_bounds__(256) void k_phi(const float* __restrict__ u,
                                             const float* __restrict__ w,
                                             float* __restrict__ phi,
                                             float* __restrict__ Cpad) {
  int t = blockIdx.x * 256 + threadIdx.x;

  if (t < PHI_THREADS) {
    int x  = t & 127;
    int y  = (t >> 7) & 127;
    int oc = (t >> 14) & 7;
    int b  = t >> 17;

    const float* up = u + (size_t)(b * NCH) * NPIX + y * IMG + x;
    const float* wr = w + oc * 8 * NCH;

    float acc[8];
#pragma unroll
    for (int k = 0; k < 8; ++k) acc[k] = 0.f;

#pragma unroll 16
    for (int i = 0; i < NCH; ++i) {
      float uv = up[(size_t)i * NPIX];
#pragma unroll
      for (int k = 0; k < 8; ++k) acc[k] += wr[k * NCH + i] * uv;
    }

    float* pp = phi + (size_t)(b * NCH + oc * 8) * PLANE + (y + PADC) * PADW + (x + PADC);
#pragma unroll
    for (int k = 0; k < 8; ++k) pp[(size_t)k * PLANE] = acc[k];
  } else if (t < PHI_THREADS + PHI_BTOTAL) {
    // phi border: rows 0..3,132..135 (all cols) + cols 0..3,132..135 (rows 4..131)
    int j = t - PHI_THREADS;
    int plane = j / PHI_BPP;
    int idx   = j - plane * PHI_BPP;
    int r, c;
    if (idx < 1088) { r = idx / 136; c = idx - (r * 136); r = (r < 4) ? r : r + 128; }
    else { int k = idx - 1088; r = (k >> 3) + 4; c = k & 7; c = (c < 4) ? c : c + 128; }
    phi[(size_t)plane * PLANE + r * PADW + c] = 0.f;
  } else if (t < TOTAL_THREADS) {
    // Cpad border: rows 0,129 (all cols) + cols 0..3,132..135 (rows 1..128)
    int j = t - (PHI_THREADS + PHI_BTOTAL);
    int plane = j / CPAD_BPP;
    int idx   = j - plane * CPAD_BPP;
    int r, c;
    if (idx < 272) { r = (idx < 136) ? 0 : 129; c = (idx < 136) ? idx : idx - 136; }
    else { int k = idx - 272; r = (k >> 3) + 1; c = k & 7; c = (c < 4) ? c : c + 128; }
    Cpad[(size_t)plane * CPLANE + r * CPW + c] = 0.f;
  }
}

// ---------------------------------------------------------------------------
// K2: partial C_d(x) = sum_{c in 16-chunk} phi[c,x]*phi[c,x+d]. 8 px/thread:
// per channel 6 float4 loads -> 56 FMAs (0.75 loads/px). Thread = (part, b,
// dy, y, 8-x half); 114688 threads = 7 waves/CU, 96 independent loads/thread.
// ---------------------------------------------------------------------------
__global__ __launch_bounds__(256) void k_corr(const float* __restrict__ phi,
                                              float* __restrict__ Cpad) {
  int t    = blockIdx.x * 256 + threadIdx.x;  // 4*2*7*128*16 = 114688 threads
  int xh   = t & 15;
  int y    = (t >> 4) & 127;
  int r    = t >> 11;           // 0..55 = part*14 + b*7 + dyI
  int part = r / 14;
  int rr   = r - part * 14;
  int b    = rr / 7;
  int dyI  = rr - b * 7;
  int x0   = xh * 8;
  int dy   = dyI - 3;

  const float* pb  = phi + (size_t)(b * NCH + part * 16) * PLANE;
  const float* own = pb + (y + PADC) * PADW + (x0 + PADC);
  const float* nb  = pb + (y + dy + PADC) * PADW + x0;   // real x = x0-4 .. x0+11

  float acc[8][7];
#pragma unroll
  for (int px = 0; px < 8; ++px)
#pragma unroll
    for (int dxi = 0; dxi < 7; ++dxi) acc[px][dxi] = 0.f;

#pragma unroll 2
  for (int c = 0; c < 16; ++c) {
    float4 o0 = *(const float4*)(own + (size_t)c * PLANE);
    float4 o1 = *(const float4*)(own + (size_t)c * PLANE + 4);
    float4 n0 = *(const float4*)(nb + (size_t)c * PLANE);
    float4 n1 = *(const float4*)(nb + (size_t)c * PLANE + 4);
    float4 n2 = *(const float4*)(nb + (size_t)c * PLANE + 8);
    float4 n3 = *(const float4*)(nb + (size_t)c * PLANE + 12);
    float ov[8]  = {o0.x, o0.y, o0.z, o0.w, o1.x, o1.y, o1.z, o1.w};
    float nv[16] = {n0.x, n0.y, n0.z, n0.w, n1.x, n1.y, n1.z, n1.w,
                    n2.x, n2.y, n2.z, n2.w, n3.x, n3.y, n3.z, n3.w};
#pragma unroll
    for (int px = 0; px < 8; ++px)
#pragma unroll
      for (int dxi = 0; dxi < 7; ++dxi)
        acc[px][dxi] += ov[px] * nv[px + dxi + 1];   // nv idx = (px+dx)+4
  }

  float* cp = Cpad + part * PSTRIDE;
#pragma unroll
  for (int dxi = 0; dxi < 7; ++dxi) {
    int d = dyI * 7 + dxi;
    float* dst = cp + ((size_t)(b * 49 + d) * CPH + (y + 1)) * CPW + (x0 + 4);
    *(float4*)dst       = make_float4(acc[0][dxi], acc[1][dxi], acc[2][dxi], acc[3][dxi]);
    *(float4*)(dst + 4) = make_float4(acc[4][dxi], acc[5][dxi], acc[6][dxi], acc[7][dxi]);
  }
}

// ---------------------------------------------------------------------------
// K2.5: S_d = box3x3(sum_part Cpad_part_d); thread = 4 consecutive x.
// ---------------------------------------------------------------------------
__global__ __launch_bounds__(256) void k_box(const float* __restrict__ Cpad,
                                             float* __restrict__ S) {
  int t  = blockIdx.x * 256 + threadIdx.x;   // 2*49*128*32 = 401408 threads
  int xq = t & 31;
  int y  = (t >> 5) & 127;
  int r  = t >> 12;             // b*49+d, 0..97
  int x0 = xq * 4;

  float acc[4] = {0.f, 0.f, 0.f, 0.f};
#pragma unroll
  for (int p = 0; p < NPART; ++p) {
    const float* base = Cpad + p * PSTRIDE + ((size_t)r * CPH + y) * CPW + x0;
#pragma unroll
    for (int ry = 0; ry < 3; ++ry) {
      const float* rp = base + ry * CPW;
      float4 a = *(const float4*)rp;
      float4 bq = *(const float4*)(rp + 4);
      float4 c = *(const float4*)(rp + 8);
      float v[12] = {a.x, a.y, a.z, a.w, bq.x, bq.y, bq.z, bq.w, c.x, c.y, c.z, c.w};
#pragma unroll
      for (int j = 0; j < 4; ++j)
        acc[j] += v[j + 3] + v[j + 4] + v[j + 5];
    }
  }

  *(float4*)(S + ((size_t)r * IMG + y) * IMG + x0) =
      make_float4(acc[0], acc[1], acc[2], acc[3]);
}

// ---------------------------------------------------------------------------
// K3: s[d] = (p+d in-image) ? S_d(p) : 0 ; softmax over 49; coalesced store
// via LDS staging. 64-thread blocks -> 512 blocks cover all 256 CUs.
// ---------------------------------------------------------------------------
__global__ __launch_bounds__(64) void k_score(const float* __restrict__ S,
                                              float* __restrict__ out) {
  __shared__ float lds[64 * 49];
  int t = blockIdx.x * 64 + threadIdx.x;     // 2*128*128 = 32768 threads
  int x = t & 127;
  int y = (t >> 7) & 127;
  int b = t >> 14;

  const float* sp = S + (size_t)b * 49 * NPIX + y * IMG + x;

  float s[49];
#pragma unroll
  for (int dyI = 0; dyI < 7; ++dyI) {
    int qy = y + dyI - 3;
    bool yv = ((unsigned)qy < (unsigned)IMG);
#pragma unroll
    for (int dxi = 0; dxi < 7; ++dxi) {
      int d  = dyI * 7 + dxi;
      int qx = x + dxi - 3;
      float v = sp[(size_t)d * NPIX];          // coalesced over x
      s[d] = (yv && ((unsigned)qx < (unsigned)IMG)) ? v : 0.f;
    }
  }

  float m = s[0];
#pragma unroll
  for (int d = 1; d < 49; ++d) m = fmaxf(m, s[d]);
  float tot = 0.f;
#pragma unroll
  for (int d = 0; d < 49; ++d) {
    float e = __expf(s[d] - m);
    s[d] = e;
    tot += e;
  }
  float inv = 1.f / tot;

#pragma unroll
  for (int d = 0; d < 49; ++d) lds[threadIdx.x * 49 + d] = s[d] * inv;
  __syncthreads();

  // block's out chunk = 64*49 = 3136 contiguous floats = 784 float4
  float* ob = out + (size_t)blockIdx.x * (64 * 49);
  const float4* l4 = (const float4*)lds;
#pragma unroll
  for (int i = 0; i < 12; ++i)                 // 12*64 = 768 float4
    ((float4*)ob)[i * 64 + threadIdx.x] = l4[i * 64 + threadIdx.x];
  if (threadIdx.x < 16)                        // remaining 16 float4
    ((float4*)ob)[768 + threadIdx.x] = l4[768 + threadIdx.x];
}

// ---------------------------------------------------------------------------
extern "C" void kernel_launch(void* const* d_in, const int* in_sizes, int n_in,
                              void* d_out, int out_size, void* d_ws, size_t ws_size,
                              hipStream_t stream) {
  const float* u = (const float*)d_in[0];
  const float* w = (const float*)d_in[1];
  float* out = (float*)d_out;

  float* phi  = (float*)d_ws;                          // 2*64*18496 = 2367488 floats
  float* Cpad = phi + (size_t)2 * NCH * PLANE;         // 4 parts * 1732640 floats
  float* S    = phi;                                   // alias: phi dead after k_corr
                                                       // (1605632 <= 2367488)

  k_phi  <<<(TOTAL_THREADS + 255) / 256, 256, 0, stream>>>(u, w, phi, Cpad);
  k_corr <<<448,  256, 0, stream>>>(phi, Cpad);
  k_box  <<<1568, 256, 0, stream>>>(Cpad, S);
  k_score<<<512,  64,  0, stream>>>(S, out);
}